// Round 5
// baseline (2007.712 us; speedup 1.0000x reference)
//
#include <hip/hip_runtime.h>
#include <math.h>

#define NN 100000
#define NE 800000
#define NH 128
#define NC 40
#define NB_SCAN 98   // ceil(NN/1024)

typedef __attribute__((ext_vector_type(8))) short short8;
typedef __attribute__((ext_vector_type(4))) float floatx4;

__device__ __forceinline__ unsigned short f2b(float f) {
  union { float f; unsigned int u; } x; x.f = f;
  unsigned int r = x.u + 0x7fff + ((x.u >> 16) & 1);  // RTNE
  return (unsigned short)(r >> 16);
}
__device__ __forceinline__ float b2f(unsigned int h16) {  // low 16 bits
  union { unsigned int u; float f; } x; x.u = h16 << 16;
  return x.f;
}

// ---------------- CSR build ----------------
__global__ void hist_kernel(const int* __restrict__ dst, int* __restrict__ cnt, int E) {
  int i = blockIdx.x * 256 + threadIdx.x;
  if (i < E) atomicAdd(&cnt[dst[i]], 1);
}

__global__ __launch_bounds__(1024) void scan1_kernel(const int* __restrict__ cnt,
                                                     int* __restrict__ rp,
                                                     int* __restrict__ bsum, int n) {
  __shared__ int buf[1024];
  int t = threadIdx.x, i = blockIdx.x * 1024 + t;
  int v = (i < n) ? cnt[i] : 0;
  buf[t] = v;
  __syncthreads();
  for (int off = 1; off < 1024; off <<= 1) {
    int x = (t >= off) ? buf[t - off] : 0;
    __syncthreads();
    buf[t] += x;
    __syncthreads();
  }
  if (i < n) rp[i] = buf[t] - v;
  if (t == 1023) bsum[blockIdx.x] = buf[t];
}

__global__ __launch_bounds__(128) void scan2_kernel(const int* __restrict__ bsum,
                                                    int* __restrict__ boff, int nb) {
  __shared__ int buf[128];
  int t = threadIdx.x;
  int v = (t < nb) ? bsum[t] : 0;
  buf[t] = v;
  __syncthreads();
  for (int off = 1; off < 128; off <<= 1) {
    int x = (t >= off) ? buf[t - off] : 0;
    __syncthreads();
    buf[t] += x;
    __syncthreads();
  }
  if (t < nb) boff[t] = buf[t] - v;
  if (t == 127) boff[nb] = buf[t];
}

__global__ void scan3_kernel(int* __restrict__ rp, const int* __restrict__ boff,
                             int n, int nb) {
  int i = blockIdx.x * 256 + threadIdx.x;
  if (i < n) rp[i] += boff[i >> 10];
  if (i == 0) rp[n] = boff[nb];
}

__global__ void copy_kernel(const int* __restrict__ a, int* __restrict__ b, int n) {
  int i = blockIdx.x * 256 + threadIdx.x;
  if (i < n) b[i] = a[i];
}

__global__ void scatter_kernel(const int* __restrict__ src, const int* __restrict__ dst,
                               const float* __restrict__ ew, int* __restrict__ off,
                               int* __restrict__ cs, float* __restrict__ cw, int E) {
  int i = blockIdx.x * 256 + threadIdx.x;
  if (i < E) {
    int p = atomicAdd(&off[dst[i]], 1);
    cs[p] = src[i];
    cw[p] = ew[i];
  }
}

// ---------------- prep: fp32 -> bf16 converts ----------------
__global__ void xconv_kernel(const float* __restrict__ in, unsigned short* __restrict__ out,
                             int n4) {
  int i = blockIdx.x * 256 + threadIdx.x;
  if (i < n4) {
    float4 v = ((const float4*)in)[i];
    out[4 * i + 0] = f2b(v.x);
    out[4 * i + 1] = f2b(v.y);
    out[4 * i + 2] = f2b(v.z);
    out[4 * i + 3] = f2b(v.w);
  }
}

// 9 dense-128 weights -> bf16, TRANSPOSED: WT[l][n][k] = W_l[k][n]
__global__ void wconv_kernel(const float* __restrict__ W1, const float* __restrict__ Wh,
                             unsigned short* __restrict__ WT) {
  int idx = blockIdx.x * 256 + threadIdx.x;  // 9*16384
  if (idx >= 9 * 16384) return;
  int l = idx >> 14, r = idx & 16383;        // r = k*128+n (coalesced read)
  int k = r >> 7, n = r & 127;
  const float* W = (l == 0) ? W1 : (Wh + (size_t)(l - 1) * 16384);
  WT[(size_t)l * 16384 + n * 128 + k] = f2b(W[r]);
}

// ---------------- spmm gather: Agg = A * Hb (bf16 in/out, fp32 acc) ----------------
// wave per node; lane handles 2 cols via packed uint; 4-way edge unroll
__global__ __launch_bounds__(256) void spmm_gather_kernel(const unsigned short* __restrict__ Hb,
                                                          const int* __restrict__ rp,
                                                          const int* __restrict__ cs,
                                                          const float* __restrict__ cw,
                                                          unsigned short* __restrict__ Agg) {
  int node = blockIdx.x * 4 + (threadIdx.x >> 6);
  int lane = threadIdx.x & 63;
  if (node >= NN) return;
  const unsigned int* H32 = (const unsigned int*)Hb;
  unsigned int* A32 = (unsigned int*)Agg;
  int e0 = rp[node], e1 = rp[node + 1];
  float al0 = 0.f, al1 = 0.f, al2 = 0.f, al3 = 0.f;
  float ah0 = 0.f, ah1 = 0.f, ah2 = 0.f, ah3 = 0.f;
  int e = e0;
  for (; e + 4 <= e1; e += 4) {
    int s0 = cs[e], s1 = cs[e + 1], s2 = cs[e + 2], s3 = cs[e + 3];
    float w0 = cw[e], w1 = cw[e + 1], w2 = cw[e + 2], w3 = cw[e + 3];
    unsigned int v0 = H32[(size_t)s0 * 64 + lane];
    unsigned int v1 = H32[(size_t)s1 * 64 + lane];
    unsigned int v2 = H32[(size_t)s2 * 64 + lane];
    unsigned int v3 = H32[(size_t)s3 * 64 + lane];
    al0 = fmaf(w0, b2f(v0 & 0xffff), al0); ah0 = fmaf(w0, b2f(v0 >> 16), ah0);
    al1 = fmaf(w1, b2f(v1 & 0xffff), al1); ah1 = fmaf(w1, b2f(v1 >> 16), ah1);
    al2 = fmaf(w2, b2f(v2 & 0xffff), al2); ah2 = fmaf(w2, b2f(v2 >> 16), ah2);
    al3 = fmaf(w3, b2f(v3 & 0xffff), al3); ah3 = fmaf(w3, b2f(v3 >> 16), ah3);
  }
  for (; e < e1; ++e) {
    unsigned int v = H32[(size_t)cs[e] * 64 + lane];
    float w = cw[e];
    al0 = fmaf(w, b2f(v & 0xffff), al0);
    ah0 = fmaf(w, b2f(v >> 16), ah0);
  }
  float lo = (al0 + al1) + (al2 + al3);
  float hi = (ah0 + ah1) + (ah2 + ah3);
  A32[(size_t)node * 64 + lane] = (unsigned int)f2b(lo) | ((unsigned int)f2b(hi) << 16);
}

// ---------------- fused MFMA layer: Hout = bf16(relu(Agg*W + b) [+ Hprev]) ----------------
// block = 256 thr (4 waves), 128 rows/block; wave w owns 64x64 quadrant
#define LDH 136  // padded LDS row stride (shorts): 272 B -> 2-way bank alias only (free)
__global__ __launch_bounds__(256) void mfma_fused_kernel(const unsigned short* __restrict__ Agg,
                                                         const unsigned short* __restrict__ WT,
                                                         const float* __restrict__ bias,
                                                         const unsigned short* __restrict__ Hprev,
                                                         unsigned short* __restrict__ Hout,
                                                         int residual) {
  __shared__ unsigned short Ws[128 * LDH];  // W^T[n][k]
  __shared__ unsigned short Hs[128 * LDH];  // 128 Agg rows
  __shared__ float bs[128];
  int tid = threadIdx.x;
  int row0 = blockIdx.x * 128;

  for (int c = tid; c < 2048; c += 256) {
    int r = c >> 4, s = c & 15;
    *(short8*)(Ws + r * LDH + s * 8) = *(const short8*)(WT + r * 128 + s * 8);
  }
  for (int c = tid; c < 2048; c += 256) {
    int r = c >> 4, s = c & 15;
    int gr = row0 + r; if (gr >= NN) gr = NN - 1;
    *(short8*)(Hs + r * LDH + s * 8) = *(const short8*)(Agg + (size_t)gr * 128 + s * 8);
  }
  if (tid < 128) bs[tid] = bias[tid];
  __syncthreads();

  int wave = tid >> 6;
  int lane = tid & 63;
  int m = lane & 15;
  int quad = lane >> 4;
  int wr0 = (wave >> 1) * 64;
  int wc0 = (wave & 1) * 64;

  floatx4 acc[4][4];
#pragma unroll
  for (int mt = 0; mt < 4; ++mt)
#pragma unroll
    for (int nt = 0; nt < 4; ++nt) acc[mt][nt] = (floatx4){0.f, 0.f, 0.f, 0.f};

#pragma unroll
  for (int ks = 0; ks < 4; ++ks) {
    short8 a[4], b[4];
#pragma unroll
    for (int mt = 0; mt < 4; ++mt)
      a[mt] = *(const short8*)(Hs + (wr0 + mt * 16 + m) * LDH + quad * 8 + ks * 32);
#pragma unroll
    for (int nt = 0; nt < 4; ++nt)
      b[nt] = *(const short8*)(Ws + (wc0 + nt * 16 + m) * LDH + quad * 8 + ks * 32);
#pragma unroll
    for (int mt = 0; mt < 4; ++mt)
#pragma unroll
      for (int nt = 0; nt < 4; ++nt)
        acc[mt][nt] = __builtin_amdgcn_mfma_f32_16x16x32_bf16(a[mt], b[nt], acc[mt][nt], 0, 0, 0);
  }
  // D: row = quad*4+reg (within 16-tile), col = m. Epilogue fused: bias+relu+residual.
#pragma unroll
  for (int mt = 0; mt < 4; ++mt) {
#pragma unroll
    for (int reg = 0; reg < 4; ++reg) {
      int gr = row0 + wr0 + mt * 16 + quad * 4 + reg;
      if (gr < NN) {
#pragma unroll
        for (int nt = 0; nt < 4; ++nt) {
          int col = wc0 + nt * 16 + m;
          float v = fmaxf(acc[mt][nt][reg] + bs[col], 0.f);
          if (residual) v += b2f(Hprev[(size_t)gr * 128 + col]);
          Hout[(size_t)gr * 128 + col] = f2b(v);
        }
      }
    }
  }
}

// ---------------- final: relu(Agg*W10 + b10) -> log_softmax -> out ----------------
// 32 rows/block, 256 thr; wave w: c=lane, rows w+4r
__global__ __launch_bounds__(256) void mfma40_lsm_kernel(const unsigned short* __restrict__ Agg,
                                                         const float* __restrict__ W10,
                                                         const float* __restrict__ b10,
                                                         float* __restrict__ out) {
  __shared__ float Wsf[128 * NC + 64];
  __shared__ float Hsf[32 * 128];  // 16 KB
  int tid = threadIdx.x;
  size_t row0 = (size_t)blockIdx.x * 32;

  for (int i = tid; i < 128 * NC / 4; i += 256) ((float4*)Wsf)[i] = ((const float4*)W10)[i];
  const uint2* A8 = (const uint2*)(Agg + row0 * NH);  // 4 bf16 per uint2
  for (int i = tid; i < 1024; i += 256) {
    uint2 v = A8[i];
    float4 f;
    f.x = b2f(v.x & 0xffff); f.y = b2f(v.x >> 16);
    f.z = b2f(v.y & 0xffff); f.w = b2f(v.y >> 16);
    ((float4*)Hsf)[i] = f;
  }
  __syncthreads();

  int c = tid & 63;
  int rg = tid >> 6;
  float acc[8];
#pragma unroll
  for (int r = 0; r < 8; ++r) acc[r] = 0.f;

  const float4* Hs4 = (const float4*)Hsf;
  for (int kk = 0; kk < 32; ++kk) {
    float4 hv[8];
#pragma unroll
    for (int r = 0; r < 8; ++r) hv[r] = Hs4[(rg + 4 * r) * 32 + kk];
#pragma unroll
    for (int j = 0; j < 4; ++j) {
      float wv = Wsf[(4 * kk + j) * NC + c];
#pragma unroll
      for (int r = 0; r < 8; ++r) {
        float s = (j == 0) ? hv[r].x : (j == 1) ? hv[r].y : (j == 2) ? hv[r].z : hv[r].w;
        acc[r] = fmaf(s, wv, acc[r]);
      }
    }
  }
  // per-row log-softmax (row's 40 cols live in lanes 0..39 of this wave)
  float bc = (c < NC) ? b10[c] : 0.f;
#pragma unroll
  for (int r = 0; r < 8; ++r) {
    float v = (c < NC) ? fmaxf(acc[r] + bc, 0.f) : -INFINITY;
    float mx = v;
#pragma unroll
    for (int off = 32; off; off >>= 1) mx = fmaxf(mx, __shfl_xor(mx, off));
    float ex = (c < NC) ? expf(v - mx) : 0.f;
    float ss = ex;
#pragma unroll
    for (int off = 32; off; off >>= 1) ss += __shfl_xor(ss, off);
    if (c < NC) out[(row0 + rg + 4 * r) * NC + c] = v - mx - logf(ss);
  }
}

extern "C" void kernel_launch(void* const* d_in, const int* in_sizes, int n_in,
                              void* d_out, int out_size, void* d_ws, size_t ws_size,
                              hipStream_t stream) {
  const float* x   = (const float*)d_in[0];
  const int*   src = (const int*)d_in[1];
  const int*   dst = (const int*)d_in[2];
  const float* ew  = (const float*)d_in[3];
  const float* W1  = (const float*)d_in[4];
  const float* Wh  = (const float*)d_in[5];
  const float* W10 = (const float*)d_in[6];
  const float* b1  = (const float*)d_in[7];
  const float* bh  = (const float*)d_in[8];
  const float* b10 = (const float*)d_in[9];
  float* out = (float*)d_out;

  // workspace layout (256B-aligned chunks), ~59 MB
  char* p = (char*)d_ws;
  int*   rp    = (int*)p;            p += (((size_t)(NN + 1) * 4 + 255) / 256) * 256;
  int*   roff  = (int*)p;            p += (((size_t)NN * 4 + 255) / 256) * 256;
  int*   bsum  = (int*)p;            p += 256 * 4;
  int*   boff  = (int*)p;            p += 256 * 4;
  int*   cs    = (int*)p;            p += (size_t)NE * 4;
  float* cw    = (float*)p;          p += (size_t)NE * 4;
  unsigned short* hb   = (unsigned short*)p; p += (size_t)NN * NH * 2;  // x-bf16 then h
  unsigned short* aggb = (unsigned short*)p; p += (size_t)NN * NH * 2;
  unsigned short* WT   = (unsigned short*)p; p += (size_t)9 * NH * NH * 2;

  // ---- build CSR ----
  hipMemsetAsync(roff, 0, (size_t)NN * 4, stream);
  hist_kernel<<<(NE + 255) / 256, 256, 0, stream>>>(dst, roff, NE);
  scan1_kernel<<<NB_SCAN, 1024, 0, stream>>>(roff, rp, bsum, NN);
  scan2_kernel<<<1, 128, 0, stream>>>(bsum, boff, NB_SCAN);
  scan3_kernel<<<(NN + 255) / 256, 256, 0, stream>>>(rp, boff, NN, NB_SCAN);
  copy_kernel<<<(NN + 255) / 256, 256, 0, stream>>>(rp, roff, NN);
  scatter_kernel<<<(NE + 255) / 256, 256, 0, stream>>>(src, dst, ew, roff, cs, cw, NE);

  // ---- prep converts ----
  xconv_kernel<<<(NN * NH / 4 + 255) / 256, 256, 0, stream>>>(x, hb, NN * NH / 4);
  wconv_kernel<<<(9 * 16384 + 255) / 256, 256, 0, stream>>>(W1, Wh, WT);

  // ---- layer 1: agg = A*x ; h = relu(agg*W1 + b1) ----
  spmm_gather_kernel<<<(NN + 3) / 4, 256, 0, stream>>>(hb, rp, cs, cw, aggb);
  mfma_fused_kernel<<<(NN + 127) / 128, 256, 0, stream>>>(aggb, WT, b1, hb, hb, 0);

  // ---- 8 hidden residual layers ----
  for (int i = 0; i < 8; ++i) {
    spmm_gather_kernel<<<(NN + 3) / 4, 256, 0, stream>>>(hb, rp, cs, cw, aggb);
    mfma_fused_kernel<<<(NN + 127) / 128, 256, 0, stream>>>(
        aggb, WT + (size_t)(i + 1) * NH * NH, bh + (size_t)i * NH, hb, hb, 1);
  }

  // ---- final layer + log_softmax ----
  spmm_gather_kernel<<<(NN + 3) / 4, 256, 0, stream>>>(hb, rp, cs, cw, aggb);
  mfma40_lsm_kernel<<<NN / 32, 256, 0, stream>>>(aggb, W10, b10, out);
}

// Round 6
// 1308.770 us; speedup vs baseline: 1.5340x; 1.5340x over previous
//
#include <hip/hip_runtime.h>
#include <math.h>

#define NN 100000
#define NE 800000
#define NH 128
#define NC 40
#define NB_SCAN 98   // ceil(NN/1024)

typedef __attribute__((ext_vector_type(8))) short short8;
typedef __attribute__((ext_vector_type(4))) float floatx4;

__device__ __forceinline__ unsigned short f2b(float f) {
  union { float f; unsigned int u; } x; x.f = f;
  unsigned int r = x.u + 0x7fff + ((x.u >> 16) & 1);  // RTNE
  return (unsigned short)(r >> 16);
}
__device__ __forceinline__ float b2f(unsigned int h16) {  // low 16 bits
  union { unsigned int u; float f; } x; x.u = h16 << 16;
  return x.f;
}

// ---------------- CSR build ----------------
__global__ void hist_kernel(const int* __restrict__ dst, int* __restrict__ cnt, int E) {
  int i = blockIdx.x * 256 + threadIdx.x;
  if (i < E) atomicAdd(&cnt[dst[i]], 1);
}

__global__ __launch_bounds__(1024) void scan1_kernel(const int* __restrict__ cnt,
                                                     int* __restrict__ rp,
                                                     int* __restrict__ bsum, int n) {
  __shared__ int buf[1024];
  int t = threadIdx.x, i = blockIdx.x * 1024 + t;
  int v = (i < n) ? cnt[i] : 0;
  buf[t] = v;
  __syncthreads();
  for (int off = 1; off < 1024; off <<= 1) {
    int x = (t >= off) ? buf[t - off] : 0;
    __syncthreads();
    buf[t] += x;
    __syncthreads();
  }
  if (i < n) rp[i] = buf[t] - v;
  if (t == 1023) bsum[blockIdx.x] = buf[t];
}

__global__ __launch_bounds__(128) void scan2_kernel(const int* __restrict__ bsum,
                                                    int* __restrict__ boff, int nb) {
  __shared__ int buf[128];
  int t = threadIdx.x;
  int v = (t < nb) ? bsum[t] : 0;
  buf[t] = v;
  __syncthreads();
  for (int off = 1; off < 128; off <<= 1) {
    int x = (t >= off) ? buf[t - off] : 0;
    __syncthreads();
    buf[t] += x;
    __syncthreads();
  }
  if (t < nb) boff[t] = buf[t] - v;
  if (t == 127) boff[nb] = buf[t];
}

__global__ void scan3_kernel(int* __restrict__ rp, const int* __restrict__ boff,
                             int n, int nb) {
  int i = blockIdx.x * 256 + threadIdx.x;
  if (i < n) rp[i] += boff[i >> 10];
  if (i == 0) rp[n] = boff[nb];
}

__global__ void copy_kernel(const int* __restrict__ a, int* __restrict__ b, int n) {
  int i = blockIdx.x * 256 + threadIdx.x;
  if (i < n) b[i] = a[i];
}

__global__ void scatter_kernel(const int* __restrict__ src, const int* __restrict__ dst,
                               const float* __restrict__ ew, int* __restrict__ off,
                               int* __restrict__ cs, float* __restrict__ cw, int E) {
  int i = blockIdx.x * 256 + threadIdx.x;
  if (i < E) {
    int p = atomicAdd(&off[dst[i]], 1);
    cs[p] = src[i];
    cw[p] = ew[i];
  }
}

// ---------------- prep: x (fp32 row-major) -> bf16 CHUNKED layout ----------------
// Hc[chunk][node][16 cols], chunk = col>>4: per-XCD-L2-resident slices (3.2 MB each)
__global__ void xconv_kernel(const float* __restrict__ in, unsigned short* __restrict__ Hc,
                             int n4) {
  int i = blockIdx.x * 256 + threadIdx.x;  // i indexes float4 over [NN,128]
  if (i < n4) {
    float4 v = ((const float4*)in)[i];
    int node = i >> 5;          // 32 float4 per row
    int q = i & 31;             // which float4
    int chunk = q >> 2;         // col0 = q*4; chunk = col0/16
    int within = (q & 3) * 4;
    unsigned short* o = Hc + ((size_t)chunk * NN + node) * 16 + within;
    o[0] = f2b(v.x); o[1] = f2b(v.y); o[2] = f2b(v.z); o[3] = f2b(v.w);
  }
}

// 9 dense-128 weights -> bf16, TRANSPOSED: WT[l][n][k] = W_l[k][n]
__global__ void wconv_kernel(const float* __restrict__ W1, const float* __restrict__ Wh,
                             unsigned short* __restrict__ WT) {
  int idx = blockIdx.x * 256 + threadIdx.x;  // 9*16384
  if (idx >= 9 * 16384) return;
  int l = idx >> 14, r = idx & 16383;        // r = k*128+n (coalesced read)
  int k = r >> 7, n = r & 127;
  const float* W = (l == 0) ? W1 : (Wh + (size_t)(l - 1) * 16384);
  WT[(size_t)l * 16384 + n * 128 + k] = f2b(W[r]);
}

// ---------------- spmm gather (chunk-partitioned): Agg = A * Hc ----------------
// grid = 8 chunks x 3125 node-groups; chunk = blockIdx&7 -> XCD round-robin affinity.
// Per wave: 8 nodes x 8 lanes; each lane owns 2 cols (1 uint = 32b) of its node's
// 16-col chunk slice. 4-way edge unroll -> 4 gathers in flight.
__global__ __launch_bounds__(256) void spmm_gather_kernel(const unsigned short* __restrict__ Hc,
                                                          const int* __restrict__ rp,
                                                          const int* __restrict__ cs,
                                                          const float* __restrict__ cw,
                                                          unsigned short* __restrict__ Agg) {
  int chunk = blockIdx.x & 7;
  int ng = blockIdx.x >> 3;
  int wave = threadIdx.x >> 6;
  int lane = threadIdx.x & 63;
  int nsub = lane >> 3;
  int csub = lane & 7;
  int node = ng * 32 + wave * 8 + nsub;
  if (node >= NN) return;
  const unsigned int* H32 = (const unsigned int*)Hc;  // 8 uints per (chunk,node)
  const size_t cbase = (size_t)chunk * NN * 8;
  int e0 = rp[node], e1 = rp[node + 1];
  float al0 = 0.f, al1 = 0.f, al2 = 0.f, al3 = 0.f;
  float ah0 = 0.f, ah1 = 0.f, ah2 = 0.f, ah3 = 0.f;
  int e = e0;
  for (; e + 4 <= e1; e += 4) {
    int s0 = cs[e], s1 = cs[e + 1], s2 = cs[e + 2], s3 = cs[e + 3];
    float w0 = cw[e], w1 = cw[e + 1], w2 = cw[e + 2], w3 = cw[e + 3];
    unsigned int v0 = H32[cbase + (size_t)s0 * 8 + csub];
    unsigned int v1 = H32[cbase + (size_t)s1 * 8 + csub];
    unsigned int v2 = H32[cbase + (size_t)s2 * 8 + csub];
    unsigned int v3 = H32[cbase + (size_t)s3 * 8 + csub];
    al0 = fmaf(w0, b2f(v0 & 0xffff), al0); ah0 = fmaf(w0, b2f(v0 >> 16), ah0);
    al1 = fmaf(w1, b2f(v1 & 0xffff), al1); ah1 = fmaf(w1, b2f(v1 >> 16), ah1);
    al2 = fmaf(w2, b2f(v2 & 0xffff), al2); ah2 = fmaf(w2, b2f(v2 >> 16), ah2);
    al3 = fmaf(w3, b2f(v3 & 0xffff), al3); ah3 = fmaf(w3, b2f(v3 >> 16), ah3);
  }
  for (; e < e1; ++e) {
    unsigned int v = H32[cbase + (size_t)cs[e] * 8 + csub];
    float w = cw[e];
    al0 = fmaf(w, b2f(v & 0xffff), al0);
    ah0 = fmaf(w, b2f(v >> 16), ah0);
  }
  float lo = (al0 + al1) + (al2 + al3);
  float hi = (ah0 + ah1) + (ah2 + ah3);
  // Agg is ROW-MAJOR [node][128] (MFMA staging wants contiguous rows)
  ((unsigned int*)Agg)[(size_t)node * 64 + chunk * 8 + csub] =
      (unsigned int)f2b(lo) | ((unsigned int)f2b(hi) << 16);
}

// ---------------- fused MFMA layer: Hc_out = bf16(relu(Agg*W + b) [+ Hc_prev]) ----------------
// block = 256 thr (4 waves), 128 rows/block; wave w owns 64x64 quadrant
#define LDH 136  // padded LDS row stride (shorts): 272 B -> 2-way bank alias only (free)
__global__ __launch_bounds__(256) void mfma_fused_kernel(const unsigned short* __restrict__ Agg,
                                                         const unsigned short* __restrict__ WT,
                                                         const float* __restrict__ bias,
                                                         const unsigned short* __restrict__ Hprev,
                                                         unsigned short* __restrict__ Hout,
                                                         int residual) {
  __shared__ unsigned short Ws[128 * LDH];  // W^T[n][k]
  __shared__ unsigned short Hs[128 * LDH];  // 128 Agg rows
  __shared__ float bs[128];
  int tid = threadIdx.x;
  int row0 = blockIdx.x * 128;

  for (int c = tid; c < 2048; c += 256) {
    int r = c >> 4, s = c & 15;
    *(short8*)(Ws + r * LDH + s * 8) = *(const short8*)(WT + r * 128 + s * 8);
  }
  for (int c = tid; c < 2048; c += 256) {
    int r = c >> 4, s = c & 15;
    int gr = row0 + r; if (gr >= NN) gr = NN - 1;
    *(short8*)(Hs + r * LDH + s * 8) = *(const short8*)(Agg + (size_t)gr * 128 + s * 8);
  }
  if (tid < 128) bs[tid] = bias[tid];
  __syncthreads();

  int wave = tid >> 6;
  int lane = tid & 63;
  int m = lane & 15;
  int quad = lane >> 4;
  int wr0 = (wave >> 1) * 64;
  int wc0 = (wave & 1) * 64;

  floatx4 acc[4][4];
#pragma unroll
  for (int mt = 0; mt < 4; ++mt)
#pragma unroll
    for (int nt = 0; nt < 4; ++nt) acc[mt][nt] = (floatx4){0.f, 0.f, 0.f, 0.f};

#pragma unroll
  for (int ks = 0; ks < 4; ++ks) {
    short8 a[4], b[4];
#pragma unroll
    for (int mt = 0; mt < 4; ++mt)
      a[mt] = *(const short8*)(Hs + (wr0 + mt * 16 + m) * LDH + quad * 8 + ks * 32);
#pragma unroll
    for (int nt = 0; nt < 4; ++nt)
      b[nt] = *(const short8*)(Ws + (wc0 + nt * 16 + m) * LDH + quad * 8 + ks * 32);
#pragma unroll
    for (int mt = 0; mt < 4; ++mt)
#pragma unroll
      for (int nt = 0; nt < 4; ++nt)
        acc[mt][nt] = __builtin_amdgcn_mfma_f32_16x16x32_bf16(a[mt], b[nt], acc[mt][nt], 0, 0, 0);
  }
  // D: row = quad*4+reg, col = wc0 + nt*16 + m -> chunk = wc0/16 + nt, within-chunk = m
  int chunk0 = wc0 >> 4;
#pragma unroll
  for (int mt = 0; mt < 4; ++mt) {
#pragma unroll
    for (int reg = 0; reg < 4; ++reg) {
      int gr = row0 + wr0 + mt * 16 + quad * 4 + reg;
      if (gr < NN) {
#pragma unroll
        for (int nt = 0; nt < 4; ++nt) {
          size_t off = ((size_t)(chunk0 + nt) * NN + gr) * 16 + m;
          float v = fmaxf(acc[mt][nt][reg] + bs[wc0 + nt * 16 + m], 0.f);
          if (residual) v += b2f(Hprev[off]);
          Hout[off] = f2b(v);
        }
      }
    }
  }
}

// ---------------- final dense matmul: [NN,128](bf16 Agg) @ [128,40] + bias + relu ----------------
__global__ __launch_bounds__(256) void matmul40_kernel(const unsigned short* __restrict__ Agg,
                                                       const float* __restrict__ W10,
                                                       const float* __restrict__ b10,
                                                       float* __restrict__ S) {
  __shared__ float Wsf[128 * NC + 64];
  __shared__ float Hsf[32 * 128];
  int tid = threadIdx.x;
  size_t row0 = (size_t)blockIdx.x * 32;

  for (int i = tid; i < 128 * NC / 4; i += 256) ((float4*)Wsf)[i] = ((const float4*)W10)[i];
  const uint2* A8 = (const uint2*)(Agg + row0 * NH);
  for (int i = tid; i < 1024; i += 256) {
    uint2 v = A8[i];
    float4 f;
    f.x = b2f(v.x & 0xffff); f.y = b2f(v.x >> 16);
    f.z = b2f(v.y & 0xffff); f.w = b2f(v.y >> 16);
    ((float4*)Hsf)[i] = f;
  }
  __syncthreads();

  int c = tid & 63;
  int rg = tid >> 6;
  float acc[8];
#pragma unroll
  for (int r = 0; r < 8; ++r) acc[r] = 0.f;

  const float4* Hs4 = (const float4*)Hsf;
  for (int kk = 0; kk < 32; ++kk) {
    float4 hv[8];
#pragma unroll
    for (int r = 0; r < 8; ++r) hv[r] = Hs4[(rg + 4 * r) * 32 + kk];
#pragma unroll
    for (int j = 0; j < 4; ++j) {
      float wv = Wsf[(4 * kk + j) * NC + c];
#pragma unroll
      for (int r = 0; r < 8; ++r) {
        float s = (j == 0) ? hv[r].x : (j == 1) ? hv[r].y : (j == 2) ? hv[r].z : hv[r].w;
        acc[r] = fmaf(s, wv, acc[r]);
      }
    }
  }
  if (c < NC) {
    float bc = b10[c];
#pragma unroll
    for (int r = 0; r < 8; ++r)
      S[(row0 + rg + 4 * r) * NC + c] = fmaxf(acc[r] + bc, 0.f);
  }
}

// ---------------- log_softmax over 40 logits per node ----------------
__global__ __launch_bounds__(256) void lsm_kernel(const float* __restrict__ S,
                                                  float* __restrict__ out) {
  int node = blockIdx.x * 4 + (threadIdx.x >> 6);
  int lane = threadIdx.x & 63;
  if (node >= NN) return;
  float v = (lane < NC) ? S[(size_t)node * NC + lane] : -INFINITY;
  float mx = v;
#pragma unroll
  for (int off = 32; off; off >>= 1) mx = fmaxf(mx, __shfl_xor(mx, off));
  float ex = (lane < NC) ? expf(v - mx) : 0.f;
  float ss = ex;
#pragma unroll
  for (int off = 32; off; off >>= 1) ss += __shfl_xor(ss, off);
  if (lane < NC) out[(size_t)node * NC + lane] = v - mx - logf(ss);
}

extern "C" void kernel_launch(void* const* d_in, const int* in_sizes, int n_in,
                              void* d_out, int out_size, void* d_ws, size_t ws_size,
                              hipStream_t stream) {
  const float* x   = (const float*)d_in[0];
  const int*   src = (const int*)d_in[1];
  const int*   dst = (const int*)d_in[2];
  const float* ew  = (const float*)d_in[3];
  const float* W1  = (const float*)d_in[4];
  const float* Wh  = (const float*)d_in[5];
  const float* W10 = (const float*)d_in[6];
  const float* b1  = (const float*)d_in[7];
  const float* bh  = (const float*)d_in[8];
  const float* b10 = (const float*)d_in[9];
  float* out = (float*)d_out;

  // workspace layout (256B-aligned chunks), ~75 MB
  char* p = (char*)d_ws;
  int*   rp    = (int*)p;            p += (((size_t)(NN + 1) * 4 + 255) / 256) * 256;
  int*   roff  = (int*)p;            p += (((size_t)NN * 4 + 255) / 256) * 256;
  int*   bsum  = (int*)p;            p += 256 * 4;
  int*   boff  = (int*)p;            p += 256 * 4;
  int*   cs    = (int*)p;            p += (size_t)NE * 4;
  float* cw    = (float*)p;          p += (size_t)NE * 4;
  unsigned short* hb   = (unsigned short*)p; p += (size_t)NN * NH * 2;  // chunked layout
  unsigned short* aggb = (unsigned short*)p; p += (size_t)NN * NH * 2;  // row-major
  float* sup40 = (float*)p;          p += (size_t)NN * NC * 4;
  unsigned short* WT   = (unsigned short*)p; p += (size_t)9 * NH * NH * 2;

  // ---- build CSR ----
  hipMemsetAsync(roff, 0, (size_t)NN * 4, stream);
  hist_kernel<<<(NE + 255) / 256, 256, 0, stream>>>(dst, roff, NE);
  scan1_kernel<<<NB_SCAN, 1024, 0, stream>>>(roff, rp, bsum, NN);
  scan2_kernel<<<1, 128, 0, stream>>>(bsum, boff, NB_SCAN);
  scan3_kernel<<<(NN + 255) / 256, 256, 0, stream>>>(rp, boff, NN, NB_SCAN);
  copy_kernel<<<(NN + 255) / 256, 256, 0, stream>>>(rp, roff, NN);
  scatter_kernel<<<(NE + 255) / 256, 256, 0, stream>>>(src, dst, ew, roff, cs, cw, NE);

  // ---- prep converts ----
  xconv_kernel<<<(NN * NH / 4 + 255) / 256, 256, 0, stream>>>(x, hb, NN * NH / 4);
  wconv_kernel<<<(9 * 16384 + 255) / 256, 256, 0, stream>>>(W1, Wh, WT);

  // ---- layer 1: agg = A*x ; h = relu(agg*W1 + b1) ----
  spmm_gather_kernel<<<8 * ((NN + 31) / 32), 256, 0, stream>>>(hb, rp, cs, cw, aggb);
  mfma_fused_kernel<<<(NN + 127) / 128, 256, 0, stream>>>(aggb, WT, b1, hb, hb, 0);

  // ---- 8 hidden residual layers ----
  for (int i = 0; i < 8; ++i) {
    spmm_gather_kernel<<<8 * ((NN + 31) / 32), 256, 0, stream>>>(hb, rp, cs, cw, aggb);
    mfma_fused_kernel<<<(NN + 127) / 128, 256, 0, stream>>>(
        aggb, WT + (size_t)(i + 1) * NH * NH, bh + (size_t)i * NH, hb, hb, 1);
  }

  // ---- final layer + log_softmax ----
  spmm_gather_kernel<<<8 * ((NN + 31) / 32), 256, 0, stream>>>(hb, rp, cs, cw, aggb);
  matmul40_kernel<<<(NN + 31) / 32, 256, 0, stream>>>(aggb, W10, b10, sup40);
  lsm_kernel<<<(NN + 3) / 4, 256, 0, stream>>>(sup40, out);
}